// Round 5
// baseline (585.810 us; speedup 1.0000x reference)
//
#include <hip/hip_runtime.h>
#include <math.h>

#define T_   50
#define B_   2048
#define NS_  12
#define NC_  4
#define NSC_ 16
#define LDC  20     // padded LDS row stride for 16-wide matrices (riccati)
#define AST  816    // per-alpha stride: 50*16=800 + 12 overflow slot + pad

__device__ __forceinline__ float dot4f(const float4 a, const float4 b) {
    return a.x*b.x + a.y*b.y + a.z*b.z + a.w*b.w;
}
__device__ __forceinline__ void axpy4(float4& acc, float s, const float4 v) {
    acc.x += s*v.x; acc.y += s*v.y; acc.z += s*v.z; acc.w += s*v.w;
}

// Wave-local sync for wave-private LDS regions: orders LDS write->read
// (lgkmcnt(0)) WITHOUT draining vmcnt, so global prefetch stays in flight.
__device__ __forceinline__ void wsync() {
    __builtin_amdgcn_wave_barrier();
    __builtin_amdgcn_s_waitcnt(0xC07F);   // vmcnt(63) expcnt(7) lgkmcnt(0)
    __builtin_amdgcn_wave_barrier();
}

// Quad (4-lane) sum via DPP quad_perm — VALU pipe, zero DS-pipe cost.
__device__ __forceinline__ float qsum(float v) {
    v += __int_as_float(__builtin_amdgcn_update_dpp(
            0, __float_as_int(v), 0xB1, 0xF, 0xF, true));  // xor 1
    v += __int_as_float(__builtin_amdgcn_update_dpp(
            0, __float_as_int(v), 0x4E, 0xF, 0xF, true));  // xor 2
    return v;
}

// ---------------------------------------------------------------------------
// Kernel 1: backward Riccati (unchanged from R4). One wave per batch element.
// ---------------------------------------------------------------------------
struct RicPref { float4 rC, rAux; };

__device__ __forceinline__ RicPref ric_load(
    const float* Cg, const float* cg, const float* Fg, const float* fg,
    int t, int b, int lane)
{
    RicPref p;
    const size_t base = (size_t)t * B_ + b;
    p.rC = ((const float4*)(Cg + base*256))[lane];
    if (lane < 48)      p.rAux = ((const float4*)(Fg + base*192))[lane];
    else if (lane < 52) p.rAux = ((const float4*)(cg + base*16))[lane-48];
    else if (lane < 55) p.rAux = ((const float4*)(fg + base*12))[lane-52];
    return p;
}

__global__ __launch_bounds__(64) void riccati_kernel(
    const float* __restrict__ Cg, const float* __restrict__ cg,
    const float* __restrict__ Fg, const float* __restrict__ fg,
    float* __restrict__ Kk)
{
    const int b    = blockIdx.x;
    const int lane = threadIdx.x;

    __shared__ __align__(16) float sV[144];
    __shared__ __align__(16) float sv[12];
    __shared__ __align__(16) float sF[12*LDC];
    __shared__ __align__(16) float sFT[16*12];
    __shared__ __align__(16) float sc[16];
    __shared__ __align__(16) float sf[12];
    __shared__ __align__(16) float sP[12*LDC];
    __shared__ __align__(16) float sQ[16*LDC];
    __shared__ __align__(16) float sq[16];
    __shared__ __align__(16) float stmp[12];
    __shared__ __align__(16) float sKT[56];
    __shared__ __align__(16) float sM[144];

    for (int i = lane; i < 144; i += 64) sV[i] = 0.f;
    if (lane < 12) sv[lane] = 0.f;

    RicPref cur = ric_load(Cg, cg, Fg, fg, T_-1, b, lane);
    wsync();

    for (int t = T_ - 1; t >= 0; --t) {
        const size_t base = (size_t)t * B_ + b;

        wsync();
        const float4 rCq = cur.rC;
        {
            const int row = lane >> 2, chx = lane & 3;
            if (lane < 48) {
                *(float4*)(sF + row*LDC + (chx<<2)) = cur.rAux;
                sFT[(4*chx+0)*12 + row] = cur.rAux.x;
                sFT[(4*chx+1)*12 + row] = cur.rAux.y;
                sFT[(4*chx+2)*12 + row] = cur.rAux.z;
                sFT[(4*chx+3)*12 + row] = cur.rAux.w;
            }
            else if (lane < 52) ((float4*)sc)[lane-48] = cur.rAux;
            else if (lane < 55) ((float4*)sf)[lane-52] = cur.rAux;
        }
        RicPref nxt = ric_load(Cg, cg, Fg, fg, (t > 0) ? t-1 : 0, b, lane);
        wsync();

        if (lane < 48) {
            const int k = lane >> 2, jc = (lane & 3) << 2;
            const float4 v0 = *(const float4*)(sV + k*12);
            const float4 v1 = *(const float4*)(sV + k*12 + 4);
            const float4 v2 = *(const float4*)(sV + k*12 + 8);
            const float vk[12] = {v0.x,v0.y,v0.z,v0.w, v1.x,v1.y,v1.z,v1.w,
                                  v2.x,v2.y,v2.z,v2.w};
            float4 acc = make_float4(0.f,0.f,0.f,0.f);
            #pragma unroll
            for (int l = 0; l < 12; ++l)
                axpy4(acc, vk[l], *(const float4*)(sF + l*LDC + jc));
            *(float4*)(sP + k*LDC + jc) = acc;
            if (jc == 0) {
                float accT = sv[k]
                    + dot4f(v0, *(const float4*)(sf))
                    + dot4f(v1, *(const float4*)(sf+4))
                    + dot4f(v2, *(const float4*)(sf+8));
                stmp[k] = accT;
            }
        }
        wsync();

        {
            const int i = lane >> 2, jc = (lane & 3) << 2;
            const float4 f0 = *(const float4*)(sFT + i*12);
            const float4 f1 = *(const float4*)(sFT + i*12 + 4);
            const float4 f2 = *(const float4*)(sFT + i*12 + 8);
            const float fcol[12] = {f0.x,f0.y,f0.z,f0.w, f1.x,f1.y,f1.z,f1.w,
                                    f2.x,f2.y,f2.z,f2.w};
            float4 acc = rCq;
            #pragma unroll
            for (int k = 0; k < 12; ++k)
                axpy4(acc, fcol[k], *(const float4*)(sP + k*LDC + jc));
            *(float4*)(sQ + i*LDC + jc) = acc;
            if (jc == 0) {
                const float accq = sc[i]
                    + dot4f(f0, *(const float4*)(stmp))
                    + dot4f(f1, *(const float4*)(stmp+4))
                    + dot4f(f2, *(const float4*)(stmp+8));
                sq[i] = accq;
                if (i >= 12) sQ[i*LDC + 16] = accq;
            }
        }
        wsync();

        {
            const float4 u0 = *(const float4*)(sQ + 12*LDC + 12);
            const float4 u1 = *(const float4*)(sQ + 13*LDC + 12);
            const float4 u2 = *(const float4*)(sQ + 14*LDC + 12);
            const float4 u3 = *(const float4*)(sQ + 15*LDC + 12);
            const float l00 = sqrtf(u0.x), i00 = 1.f/l00;
            const float l10 = u0.y*i00, l20 = u0.z*i00, l30 = u0.w*i00;
            const float l11 = sqrtf(u1.y - l10*l10), i11 = 1.f/l11;
            const float l21 = (u1.z - l20*l10)*i11;
            const float l31 = (u1.w - l30*l10)*i11;
            const float l22 = sqrtf(u2.z - l20*l20 - l21*l21), i22 = 1.f/l22;
            const float l32 = (u2.w - l30*l20 - l31*l21)*i22;
            const float l33 = sqrtf(u3.w - l30*l30 - l31*l31 - l32*l32), i33 = 1.f/l33;
            if (lane < 13) {
                const int cidx = (lane < 12) ? lane : 16;
                const float r0 = sQ[12*LDC + cidx];
                const float r1 = sQ[13*LDC + cidx];
                const float r2 = sQ[14*LDC + cidx];
                const float r3 = sQ[15*LDC + cidx];
                const float y0 = r0*i00;
                const float y1 = (r1 - l10*y0)*i11;
                const float y2 = (r2 - l20*y0 - l21*y1)*i22;
                const float y3 = (r3 - l30*y0 - l31*y1 - l32*y2)*i33;
                const float z3 = y3*i33;
                const float z2 = (y2 - l32*z3)*i22;
                const float z1 = (y1 - l21*z2 - l31*z3)*i11;
                const float z0 = (y0 - l10*z1 - l20*z2 - l30*z3)*i00;
                *(float4*)(sKT + lane*4) = make_float4(-z0,-z1,-z2,-z3);
            }
        }
        wsync();

        if (lane < 52) {
            float val;
            if (lane < 48) {
                const int i2 = lane / 12, j2 = lane - i2*12;
                val = sKT[j2*4 + i2];
            } else val = sKT[lane];
            (Kk + base*52)[lane] = val;
        }
        if (lane < 36) {
            const int i = lane / 3, jc = (lane % 3) << 2;
            const float4 kv = *(const float4*)(sKT + i*4);
            float4 acc = make_float4(0.f,0.f,0.f,0.f);
            axpy4(acc, kv.x, *(const float4*)(sQ + 12*LDC + jc));
            axpy4(acc, kv.y, *(const float4*)(sQ + 13*LDC + jc));
            axpy4(acc, kv.z, *(const float4*)(sQ + 14*LDC + jc));
            axpy4(acc, kv.w, *(const float4*)(sQ + 15*LDC + jc));
            *(float4*)(sM + i*12 + jc) = acc;
        } else if (lane < 48) {
            const int i = lane - 36;
            const float4 qxu = *(const float4*)(sQ + i*LDC + 12);
            const float4 kk4 = *(const float4*)(sKT + 48);
            sv[i] = sq[i] + dot4f(qxu, kk4);
        }
        wsync();

        if (lane < 36) {
            const int i = lane / 3, jc = (lane % 3) << 2;
            const float4 q  = *(const float4*)(sQ + i*LDC + jc);
            const float4 m1 = *(const float4*)(sM + i*12 + jc);
            const float t0 = sM[(jc+0)*12 + i];
            const float t1 = sM[(jc+1)*12 + i];
            const float t2 = sM[(jc+2)*12 + i];
            const float t3 = sM[(jc+3)*12 + i];
            float4 rr;
            rr.x = q.x + 0.5f*(m1.x + t0);
            rr.y = q.y + 0.5f*(m1.y + t1);
            rr.z = q.z + 0.5f*(m1.z + t2);
            rr.w = q.w + 0.5f*(m1.w + t3);
            *(float4*)(sV + i*12 + jc) = rr;
        }
        cur = nxt;
    }
}

// ---------------------------------------------------------------------------
// Kernel 2: rollout, alpha-parallel. One wave per (batch, alpha): 10240 waves
// -> ~30 waves/CU (was 8). Block = 5 waves (320 thr) sharing staus/sunom.
// Quad layout per wave: r=lane>>2 (tau row 0..15), ch=lane&3 (chunk).
// Unified G=[F;K] row so x' and u share one dot path. 5 DS instr/step.
// ---------------------------------------------------------------------------
struct RW { float4 C4, G4; float cr, gr; };

__device__ __forceinline__ RW rw_load(
    const float* __restrict__ Cg, const float* __restrict__ cg,
    const float* __restrict__ Fg, const float* __restrict__ fg,
    const float* __restrict__ Kg,
    int t, int b, int lane, int r, int ch)
{
    RW p;
    const size_t base = (size_t)t * B_ + b;
    p.C4 = ((const float4*)(Cg + base*256))[lane];   // C[r][4ch..]
    p.cr = cg[base*16 + r];
    if (r < 12) {
        p.G4 = ((const float4*)(Fg + base*192))[lane];  // F[r][4ch..]
        p.gr = fg[base*12 + r];
    } else {
        if (ch < 3) p.G4 = *(const float4*)(Kg + base*52 + (r-12)*12 + 4*ch);
        else        p.G4 = make_float4(0.f,0.f,0.f,0.f);  // K row cols 12..15
        p.gr = Kg[base*52 + 48 + (r-12)];                 // kk
    }
    return p;
}

__global__ __launch_bounds__(320, 8) void rollout_kernel(
    const float* __restrict__ x0g, const float* __restrict__ Cg,
    const float* __restrict__ cg,  const float* __restrict__ Fg,
    const float* __restrict__ fg,  const float* __restrict__ Kk,
    float* __restrict__ outg)
{
    const int b    = blockIdx.x;
    const int tid  = threadIdx.x;
    const int a    = tid >> 6;          // alpha = wave index
    const int lane = tid & 63;
    const int r = lane >> 2, ch = lane & 3;
    const float alpha = ldexpf(1.f, -a);   // 0.5^a

    __shared__ __align__(16) float staus[5*AST];   // per-alpha [t][16]
    __shared__ __align__(16) float sunom[T_*NC_];  // [t][4]
    __shared__ float scost[5];
    float* sta = staus + a*AST;

    if (tid < T_*NC_) sunom[tid] = 0.f;
    if (lane < 12) sta[lane] = x0g[b*12 + lane];   // x0 -> tau[0] x-part
    RW cur = rw_load(Cg, cg, Fg, fg, Kk, 0, b, lane, r, ch);
    __syncthreads();

    for (int iter = 0; iter < 3; ++iter) {
        float cacc = 0.f;

        for (int t = 0; t < T_; ++t) {
            // ---- phase 1: x chunks, u-lanes compute & publish u ----
            float4 c4 = *(const float4*)(sta + t*16 + (ch<<2));  // ch==3: stale, unused
            const int   ui = (r >= 12) ? (r - 12) : 0;
            const float un = sunom[t*4 + ui];
            const float pG1 = (ch < 3) ? dot4f(cur.G4, c4) : 0.f;
            float       pCt = (ch < 3) ? dot4f(cur.C4, c4) : 0.f;
            const float q1  = qsum(pG1);   // u-rows: K·x ; x-rows: F·x partial
            if (r >= 12 && ch == 0) {
                float u = (1.f - alpha)*un + alpha*(q1 + cur.gr);
                u = fminf(1.f, fmaxf(-1.f, u));
                sta[t*16 + 12 + (r - 12)] = u;
            }
            RW nxt = rw_load(Cg, cg, Fg, fg, Kk,
                             (t+1 < T_) ? t+1 : 0, b, lane, r, ch);
            wsync();   // u publish -> u4 read

            // ---- phase 2: u chunk, finish dots, cost, publish x' ----
            const float4 u4 = *(const float4*)(sta + t*16 + 12);  // broadcast
            if (ch == 3) { c4 = u4; pCt = dot4f(cur.C4, u4); }
            const float q2 = qsum((ch == 3) ? dot4f(cur.G4, u4) : 0.f);
            const float cc = qsum(pCt);                 // (C tau)_r
            if (r < 12 && ch == 0)
                sta[(t+1)*16 + r] = q1 + q2 + cur.gr;   // x'_r (t=49 -> pad slot)
            if (ch == (r >> 2)) {                       // diagonal lane holds tau_r
                const int  sel  = r & 3;
                const float taur = (sel == 0) ? c4.x : (sel == 1) ? c4.y
                                  : (sel == 2) ? c4.z : c4.w;
                cacc += (0.5f*cc + cur.cr) * taur;
            }
            cur = nxt;
            wsync();   // x' publish -> next step's phase-1 read
        } // t

        // ---- per-alpha cost reduce; cross-wave argmin (first-min) ----
        float v = cacc;
        #pragma unroll
        for (int off = 1; off < 64; off <<= 1) v += __shfl_xor(v, off, 64);
        if (lane == 0) scost[a] = v;
        __syncthreads();
        int best = 0; float bc = scost[0];
        #pragma unroll
        for (int a2 = 1; a2 < 5; ++a2)
            if (scost[a2] < bc) { bc = scost[a2]; best = a2; }

        // ---- u_nom <- best alpha's u; final iter: write best taus out ----
        if (tid < T_*NC_)
            sunom[tid] = staus[best*AST + (tid >> 2)*16 + 12 + (tid & 3)];
        if (iter == 2 && tid < 200) {
            const int tt = tid >> 2, jo = (tid & 3) << 2;
            *(float4*)(outg + ((size_t)tt*B_ + b)*16 + jo) =
                *(const float4*)(staus + best*AST + tt*16 + jo);
        }
        __syncthreads();
    } // iter
}

extern "C" void kernel_launch(void* const* d_in, const int* in_sizes, int n_in,
                              void* d_out, int out_size, void* d_ws, size_t ws_size,
                              hipStream_t stream) {
    const float* x0 = (const float*)d_in[0];
    const float* C  = (const float*)d_in[1];
    const float* c  = (const float*)d_in[2];
    const float* F  = (const float*)d_in[3];
    const float* f  = (const float*)d_in[4];
    float* out = (float*)d_out;
    float* Kk  = (float*)d_ws;   // 50*2048*52*4 = 21.3 MB

    riccati_kernel<<<B_, 64, 0, stream>>>(C, c, F, f, Kk);
    rollout_kernel<<<B_, 320, 0, stream>>>(x0, C, c, F, f, Kk, out);
}